// Round 1
// baseline (181.065 us; speedup 1.0000x reference)
//
#include <hip/hip_runtime.h>

#define NRBF 20
#define FOUT 16
#define NA 768
#define NB 4

// Round-4 change: wave-uniform f-quad -> W lives in SGPRs.
//   Old mapping: fq = tid&3 (per-lane) forced 80 W floats into VGPRs (wk[20]
//   float4 = 80 VGPR) -> VGPR-count capped occupancy at ~3 waves/SIMD, and the
//   serial d->sqrt->exp->recurrence chain stalled with too few waves resident.
//   New mapping: fq = tid>>6 (wave id), m_local = tid&63 (lane). W row for the
//   wave's 4 f's (80 floats + 4 bias) is wave-invariant -> readfirstlane pins
//   it in SGPRs; inner FMA is v_fmac_f32 v,s,v (1 SGPR src, legal).
//   VGPR drops to the ~50-80 range -> __launch_bounds__(256,6) = 6 waves/SIMD.
// Store pattern: lane l stores 16B at 64B stride (offset l*64B + w*16B); the
//   block's 4 waves jointly fill every 128B line back-to-back, merged in L2.
//   ~4x coalescer granules on stores costs ~4us chip-wide -- cheap vs 2x waves.
// RBF via geometric recurrence unchanged: r_k = r_{k-1}*t, t *= e^{-0.2},
//   r_0 = e^{-10 d^2}, t_1 = e^{2d-0.1}  (telescoped -10(d-0.1k)^2).

__device__ __forceinline__ float rfl(float x) {
    return __int_as_float(__builtin_amdgcn_readfirstlane(__float_as_int(x)));
}

__global__ __launch_bounds__(256, 6) void cfconv_kernel(
    const float* __restrict__ coords,  // [NB, NA, 3] fp32
    const float* __restrict__ Ww,      // [FOUT, NRBF] fp32
    const float* __restrict__ Wb,      // [FOUT] fp32
    float* __restrict__ out)           // [NB, NA, NA, FOUT] fp32
{
    __shared__ float Wt[NRBF * FOUT];      // transposed: Wt[k*16 + f]
    __shared__ float cm[NA * 3];           // all 768 m-coordinates for batch b

    const int tid = threadIdx.x;
    const int n   = blockIdx.x;
    const int b   = blockIdx.y;

    // one-time: transpose W into LDS (Ww is [f][k] row-major -> Wt[k][f])
    for (int i = tid; i < NRBF * FOUT; i += 256) {
        int k = i >> 4, f = i & 15;
        Wt[i] = Ww[f * NRBF + k];
    }
    // one-time: stage the batch's coordinate row (2304 floats, coalesced)
    const float* cb = coords + (size_t)b * NA * 3;
    for (int i = tid; i < NA * 3; i += 256) cm[i] = cb[i];
    __syncthreads();

    const int w = tid >> 6;   // wave id == f-quad this wave owns
    const int l = tid & 63;   // lane == m offset within each 64-m tile

    // Wave-uniform W fragment (4 f x 20 k) + bias -> SGPRs via readfirstlane.
    // LDS reads below are same-address across the wave (broadcast, no conflict).
    float s0[NRBF], s1[NRBF], s2[NRBF], s3[NRBF];
    #pragma unroll
    for (int k = 0; k < NRBF; ++k) {
        s0[k] = rfl(Wt[k * FOUT + 4 * w + 0]);
        s1[k] = rfl(Wt[k * FOUT + 4 * w + 1]);
        s2[k] = rfl(Wt[k * FOUT + 4 * w + 2]);
        s3[k] = rfl(Wt[k * FOUT + 4 * w + 3]);
    }
    const float b0 = rfl(Wb[4 * w + 0]);
    const float b1 = rfl(Wb[4 * w + 1]);
    const float b2 = rfl(Wb[4 * w + 2]);
    const float b3 = rfl(Wb[4 * w + 3]);

    const float xn = cb[n * 3 + 0];   // uniform per block (scalar loads)
    const float yn = cb[n * 3 + 1];
    const float zn = cb[n * 3 + 2];

    const float u = 0.81873075308f;   // e^{-0.2}
    float* orow = out + (((size_t)b * NA + n) * NA) * FOUT + l * FOUT + w * 4;

    #pragma unroll 4
    for (int j = 0; j < NA / 64; ++j) {
        const int m = j * 64 + l;
        // cm word index 3m: gcd(3,32)=1 -> lanes l and l+32 alias per bank
        // (2-way, free); all other lanes hit distinct banks.
        const float dx = xn - cm[m * 3 + 0];
        const float dy = yn - cm[m * 3 + 1];
        const float dz = zn - cm[m * 3 + 2];
        const float d2 = dx * dx + dy * dy + dz * dz;
        const float d  = sqrtf(d2);

        float r = __expf(-10.0f * d2);       // r_0
        float t = __expf(2.0f * d - 0.1f);   // t_1

        float a0 = fmaf(r, s0[0], b0);
        float a1 = fmaf(r, s1[0], b1);
        float a2 = fmaf(r, s2[0], b2);
        float a3 = fmaf(r, s3[0], b3);
        #pragma unroll
        for (int k = 1; k < NRBF; ++k) {
            r *= t;                          // r_k = r_{k-1} * t_k
            t *= u;                          // t_{k+1} = t_k * e^{-0.2}
            a0 = fmaf(r, s0[k], a0);
            a1 = fmaf(r, s1[k], a1);
            a2 = fmaf(r, s2[k], a2);
            a3 = fmaf(r, s3[k], a3);
        }

        float4 v; v.x = a0; v.y = a1; v.z = a2; v.w = a3;
        *reinterpret_cast<float4*>(orow + (size_t)j * 64 * FOUT) = v;
    }
}

extern "C" void kernel_launch(void* const* d_in, const int* in_sizes, int n_in,
                              void* d_out, int out_size, void* d_ws, size_t ws_size,
                              hipStream_t stream) {
    const float* coords = (const float*)d_in[0];
    const float* Ww     = (const float*)d_in[1];
    const float* Wb     = (const float*)d_in[2];
    float* out          = (float*)d_out;

    dim3 grid(NA, NB);   // (n, b)
    cfconv_kernel<<<grid, 256, 0, stream>>>(coords, Ww, Wb, out);
}

// Round 2
// 160.553 us; speedup vs baseline: 1.1278x; 1.1278x over previous
//
#include <hip/hip_runtime.h>

#define NRBF 20
#define FOUT 16
#define NA 768
#define NB 4

// Round-5: move the k-contraction onto the MFMA pipe.
//   out[m, f] = sum_k rbf(d_m, k) * W[f, k] + b[f]  is a [64x20]@[20x16] GEMM
//   per 64-m tile -> mfma_f32_16x16x32_f16 (K zero-padded 20->32, N=16 exact).
//
// Gauge trick (removes A/B layout risk): the MFMA's (lane-group, elem)->k map
//   is arbitrary as long as A and B fragments use the SAME labeling, because
//   the HW sums over all 64 positions. We pick k = (lane>>4)*8 + j. Only the
//   C/D layout must be exact, and that one is HW-verified:
//   col = lane&15 (f), row = (lane>>4)*4 + reg (m within tile).
//
// Per lane: m = lane&15 (A row), k-segment = (lane>>4)*8 .. +7. The geometric
//   recurrence r_{k+1} = r_k * t, t *= e^{-0.2} now runs only 7 serial steps
//   (k-parallel across lane groups) -> shorter dependency chain AND less drift.
//   r_{k0} = e^{-10(d-0.1 k0)^2}, t_{k0+1} = e^{2d - 0.2 k0 - 0.1}.
// fp16 fragments (not bf16): 10 mantissa bits, rbf in [0,1], W ~ N(0,0.22),
//   f32 accumulate -> ~1e-3 abs error, well under the passing 0.0078.
// VALU per wave drops ~1680 -> ~550 instrs + 12 MFMA; VGPR ~55 ->
//   __launch_bounds__(256,8) = 8 waves/SIMD for latency hiding.

typedef _Float16 f16x8 __attribute__((ext_vector_type(8)));
typedef float    f32x4 __attribute__((ext_vector_type(4)));

__global__ __launch_bounds__(256, 8) void cfconv_kernel(
    const float* __restrict__ coords,  // [NB, NA, 3] fp32
    const float* __restrict__ Ww,      // [FOUT, NRBF] fp32
    const float* __restrict__ Wb,      // [FOUT] fp32
    float* __restrict__ out)           // [NB, NA, NA, FOUT] fp32
{
    __shared__ float cm[NA * 3];       // all 768 m-coordinates for batch b

    const int tid = threadIdx.x;
    const int n   = blockIdx.x;
    const int b   = blockIdx.y;

    const float* cb = coords + (size_t)b * NA * 3;
    for (int i = tid; i < NA * 3; i += 256) cm[i] = cb[i];
    __syncthreads();

    const int w  = tid >> 6;    // wave id 0..3
    const int l  = tid & 63;    // lane
    const int fr = l & 15;      // A row (m sub-index) / B col (f) / C col (f)
    const int g  = l >> 4;      // k-group: our gauge k = g*8 + j

    // B fragment: B[k][f] = W[f][k] for k<20 else 0. Built once (L2-hot array).
    f16x8 bfrag;
    #pragma unroll
    for (int j = 0; j < 8; ++j) {
        const int k = g * 8 + j;
        bfrag[j] = (k < NRBF) ? (_Float16)Ww[fr * NRBF + k] : (_Float16)0.0f;
    }
    const float bias = Wb[fr];

    const float xn = cb[n * 3 + 0];   // block-uniform -> scalar loads
    const float yn = cb[n * 3 + 1];
    const float zn = cb[n * 3 + 2];

    const float mu0  = 0.1f * (8 * g);          // segment-start mu
    const float tcst = 0.2f * (8 * g) + 0.1f;   // t_{k0+1} exponent offset
    const float u    = 0.81873075308f;          // e^{-0.2}

    float* orow  = out + ((size_t)b * NA + n) * NA * FOUT;
    // lane's store base: row-in-tile = g*4 + reg, col = fr
    float* obase = orow + (size_t)(g * 4) * FOUT + fr;

    // wave w owns m-tiles (t*4 + w)*16 : 12 tiles of 16 m -> 192 m per wave
    #pragma unroll 2
    for (int t = 0; t < 12; ++t) {
        const int m0 = (t * 4 + w) * 16;
        const int m  = m0 + fr;
        // cm word index 3m: 16 lanes stride-3 -> all distinct banks (gcd(3,32)=1);
        // lane groups share addresses -> broadcast, no conflict.
        const float dx = xn - cm[m * 3 + 0];
        const float dy = yn - cm[m * 3 + 1];
        const float dz = zn - cm[m * 3 + 2];
        const float d2 = fmaf(dx, dx, fmaf(dy, dy, dz * dz));
        const float d  = sqrtf(d2);

        const float dd = d - mu0;
        float r  = __expf(-10.0f * dd * dd);    // r_{k0}
        float tt = __expf(2.0f * d - tcst);     // ratio t_{k0+1}

        f16x8 afrag;
        afrag[0] = (_Float16)r;
        #pragma unroll
        for (int j = 1; j < 8; ++j) {
            r *= tt;                            // r_{k0+j}
            tt *= u;
            afrag[j] = (_Float16)r;
        }

        f32x4 acc = {bias, bias, bias, bias};   // C-in = bias (broadcast over m)
        acc = __builtin_amdgcn_mfma_f32_16x16x32_f16(afrag, bfrag, acc, 0, 0, 0);

        // C: element (m0 + g*4 + reg, fr); 16 lanes per reg write one 64B row
        float* p = obase + (size_t)m0 * FOUT;
        p[0 * FOUT] = acc[0];
        p[1 * FOUT] = acc[1];
        p[2 * FOUT] = acc[2];
        p[3 * FOUT] = acc[3];
    }
}

extern "C" void kernel_launch(void* const* d_in, const int* in_sizes, int n_in,
                              void* d_out, int out_size, void* d_ws, size_t ws_size,
                              hipStream_t stream) {
    const float* coords = (const float*)d_in[0];
    const float* Ww     = (const float*)d_in[1];
    const float* Wb     = (const float*)d_in[2];
    float* out          = (float*)d_out;

    dim3 grid(NA, NB);   // (n, b)
    cfconv_kernel<<<grid, 256, 0, stream>>>(coords, Ww, Wb, out);
}